// Round 13
// baseline (181.290 us; speedup 1.0000x reference)
//
#include <hip/hip_runtime.h>
#include <stdint.h>

// ---------------- types & helpers ----------------
typedef __bf16   bf16x8 __attribute__((ext_vector_type(8)));
typedef float    f32x4  __attribute__((ext_vector_type(4)));
typedef float    f32x16 __attribute__((ext_vector_type(16)));
typedef uint16_t u16x8  __attribute__((ext_vector_type(8)));
typedef uint16_t u16x4  __attribute__((ext_vector_type(4)));
typedef uint32_t u32x4  __attribute__((ext_vector_type(4)));

#define DEVFN static __device__ __forceinline__

DEVFN uint16_t f2bf(float f){            // RNE f32 -> bf16
  uint32_t u = __builtin_bit_cast(uint32_t, f);
  u += 0x7fffu + ((u >> 16) & 1u);
  return (uint16_t)(u >> 16);
}
DEVFN float bf2f(uint16_t h){
  return __builtin_bit_cast(float, (uint32_t)h << 16);
}
DEVFN bf16x8 ldbf8(const uint16_t* p){
  return __builtin_bit_cast(bf16x8, *(const u16x8*)p);
}
DEVFN void gl16(const void* g, void* l){ // async global->LDS, 16B/lane, LDS base wave-uniform
  __builtin_amdgcn_global_load_lds((__attribute__((address_space(1))) void*)g,
                                   (__attribute__((address_space(3))) void*)l,
                                   16, 0, 0);
}
DEVFN f32x4 mfma16(bf16x8 a, bf16x8 b, f32x4 c){
  return __builtin_amdgcn_mfma_f32_16x16x32_bf16(a, b, c, 0, 0, 0);
}
DEVFN f32x16 mfma32(bf16x8 a, bf16x8 b, f32x16 c){
  return __builtin_amdgcn_mfma_f32_32x32x16_bf16(a, b, c, 0, 0, 0);
}
DEVFN uint32_t cvtpk(float lo, float hi){          // pack 2 f32 -> 2 bf16 in one dword
  uint32_t r;
  asm("v_cvt_pk_bf16_f32 %0, %1, %2" : "=v"(r) : "v"(lo), "v"(hi));
  return r;
}
DEVFN void plswap(uint32_t &x, uint32_t &y){       // swap x.hi-lanes <-> y.lo-lanes
  asm("v_permlane32_swap_b32 %0, %1" : "+v"(x), "+v"(y));
}

// ---------------- mask dtype detect + expand ----------------
__global__ void detect_mask_k(const uint32_t* m, int* flag){
  int i = blockIdx.x * 256 + threadIdx.x;          // 16 blocks x 256 = 4096 dwords
  uint32_t v = m[i];
  int notint   = (v > 1u) ? 1 : 0;
  int notfloat = (v != 0u && v != 0x3F800000u) ? 2 : 0;
  int bits = notint | notfloat;
  if (__any(bits)){
    int agg = bits;
    agg |= __shfl_xor(agg, 1);  agg |= __shfl_xor(agg, 2);
    agg |= __shfl_xor(agg, 4);  agg |= __shfl_xor(agg, 8);
    agg |= __shfl_xor(agg, 16); agg |= __shfl_xor(agg, 32);
    if ((threadIdx.x & 63) == 0) atomicOr(flag, agg);
  }
}

__global__ void expand_mask_k(const void* m, const int* flag, float* bias){
  int i = blockIdx.x * 256 + threadIdx.x;   // 16384 elements
  int f = *flag;
  bool on;
  if ((f & 1) == 0)      on = ((const int*)m)[i]   != 0;     // int32
  else if ((f & 2) == 0) on = ((const float*)m)[i] != 0.0f;  // float32
  else                   on = ((const uint8_t*)m)[i] != 0;   // bool bytes
  bias[i] = on ? 0.0f : -1e30f;
}

// ---------------- RMSNorm (f32 in) -> bf16 out, x and mem fused ----------------
__global__ __launch_bounds__(256) void rmsnorm_k(const float* __restrict__ x,
                                                 const float* __restrict__ mem,
                                                 uint16_t* __restrict__ xn,
                                                 uint16_t* __restrict__ mn,
                                                 const float* __restrict__ scale){
  int row = blockIdx.x;                 // 0..20479: first 4096 -> x, rest -> mem
  const float* in; uint16_t* out; int r0;
  if (row < 4096){ in = x;  out = xn; r0 = row; }
  else           { in = mem; out = mn; r0 = row - 4096; }
  const float4* ip = (const float4*)(in + (size_t)r0 * 1024);
  float4 v = ip[threadIdx.x];
  float ss = v.x*v.x + v.y*v.y + v.z*v.z + v.w*v.w;
  #pragma unroll
  for (int off = 1; off < 64; off <<= 1) ss += __shfl_xor(ss, off);
  __shared__ float wsum[4];
  if ((threadIdx.x & 63) == 0) wsum[threadIdx.x >> 6] = ss;
  __syncthreads();
  float r = rsqrtf((wsum[0] + wsum[1] + wsum[2] + wsum[3]) * (1.0f/1024.0f) + 1e-6f);
  float4 sc = ((const float4*)scale)[threadIdx.x];
  u16x4 o;
  o[0] = f2bf(v.x * r * (1.0f + sc.x));
  o[1] = f2bf(v.y * r * (1.0f + sc.y));
  o[2] = f2bf(v.z * r * (1.0f + sc.z));
  o[3] = f2bf(v.w * r * (1.0f + sc.w));
  *(u16x4*)(out + (size_t)r0 * 1024 + threadIdx.x * 4) = o;
}

// ---------------- transpose+cast: all three weights in one launch ----------------
__global__ void transpose_cast_all_k(const float* __restrict__ qw,
                                     const float* __restrict__ kvw,
                                     const float* __restrict__ ow,
                                     uint16_t* __restrict__ wq,
                                     uint16_t* __restrict__ wkv,
                                     uint16_t* __restrict__ wout){
  int z = blockIdx.z;
  const float* in; uint16_t* out; int rs, os, C;
  if (z < 4)      { in = qw  + z*262144;     out = wq  + z*262144;     rs = 256;  os = 1024; C = 256; }
  else if (z < 6) { in = kvw + (z-4)*262144; out = wkv + (z-4)*262144; rs = 256;  os = 1024; C = 256; }
  else            { in = ow;                 out = wout;               rs = 1024; os = 1024; C = 1024; }
  int c0 = blockIdx.x * 32, r0 = blockIdx.y * 32;
  if (c0 >= C) return;
  __shared__ float t[32][33];
  int tx = threadIdx.x, ty = threadIdx.y;     // (32,8)
  #pragma unroll
  for (int i = 0; i < 4; ++i)
    t[ty + 8*i][tx] = in[(size_t)(r0 + ty + 8*i) * rs + c0 + tx];
  __syncthreads();
  #pragma unroll
  for (int i = 0; i < 4; ++i)
    out[(size_t)(c0 + ty + 8*i) * os + r0 + tx] = f2bf(t[tx][ty + 8*i]);
}

// ---------------- RoPE q+k in one launch (in-place on bf16) ----------------
__global__ __launch_bounds__(256) void rope_all_k(uint16_t* q, uint16_t* kk){
  if (blockIdx.x < 8192){
    int idx = blockIdx.x * 256 + threadIdx.x;   // 2M q pairs
    int j = idx & 127, n = (idx >> 7) & 3, bt = idx >> 9;
    float inv = exp2f((float)j * (-13.287712379549449f / 128.0f)); // 10000^(-j/128)
    float rad = (float)(2048 + (bt & 511)) * inv;
    float s, c; sincosf(rad, &s, &c);
    size_t base = (size_t)bt * 1024 + n * 256 + j;
    float x1 = bf2f(q[base]), x2 = bf2f(q[base + 128]);
    q[base]       = f2bf((x1 * c - x2 * s) * 0.0625f);
    q[base + 128] = f2bf((x2 * c + x1 * s) * 0.0625f);
  } else {
    int idx = (blockIdx.x - 8192) * 256 + threadIdx.x;  // 2M k pairs
    int j = idx & 127, bs = idx >> 7;
    float inv = exp2f((float)j * (-13.287712379549449f / 128.0f));
    float rad = (float)(bs & 2047) * inv;
    float s, c; sincosf(rad, &s, &c);
    size_t base = (size_t)bs * 256 + j;
    float x1 = bf2f(kk[base]), x2 = bf2f(kk[base + 128]);
    kk[base]       = f2bf(x1 * c - x2 * s);
    kk[base + 128] = f2bf(x2 * c + x1 * s);
  }
}

// ---------------- shared GEMM body: BK=64, XOR-swizzled LDS (16-way fix) ----------------
// As/Bs rows are 128B -> linear layout would be a 16-way b128 conflict (G4);
// XOR byte ^ ((row&7)<<4) via pre-swizzled gl16 source + swizzled read.
#define GEMM_BODY(A_, Bt_, K_)                                                  \
  __shared__ __align__(16) uint16_t As[128*64];                                 \
  __shared__ __align__(16) uint16_t Bs[128*64];                                 \
  f32x4 acc[4][4] = {};                                                         \
  {                                                                             \
    const int K = (K_);                                                         \
    _Pragma("unroll 1")                                                         \
    for (int k0 = 0; k0 < K; k0 += 64){                                         \
      __syncthreads();                                                          \
      _Pragma("unroll")                                                         \
      for (int it = 0; it < 4; ++it){                                           \
        int ob = it * 4096 + tid * 16;                                          \
        int row = ob >> 7;                                                      \
        int col = (ob & 127) ^ ((row & 7) << 4);                                \
        gl16((const char*)(A_)  + ((size_t)(m0 + row) * K + k0) * 2 + col,      \
             (char*)As + it * 4096 + wid * 1024);                               \
        gl16((const char*)(Bt_) + ((size_t)(n0 + row) * K + k0) * 2 + col,      \
             (char*)Bs + it * 4096 + wid * 1024);                               \
      }                                                                         \
      __syncthreads();                                                          \
      bf16x8 af[2][4], bfr[2][4];                                               \
      _Pragma("unroll")                                                         \
      for (int ks = 0; ks < 2; ++ks){                                           \
        _Pragma("unroll")                                                       \
        for (int m = 0; m < 4; ++m)                                             \
          af[ks][m]  = ldbf8(&As[(wr*64 + m*16 + lr) * 64 +                     \
                                 ((ks*32 + lq*8) ^ ((lr & 7) << 3))]);          \
        _Pragma("unroll")                                                       \
        for (int n = 0; n < 4; ++n)                                             \
          bfr[ks][n] = ldbf8(&Bs[(wc*64 + n*16 + lr) * 64 +                     \
                                 ((ks*32 + lq*8) ^ ((lr & 7) << 3))]);          \
      }                                                                         \
      _Pragma("unroll")                                                         \
      for (int ks = 0; ks < 2; ++ks)                                            \
        _Pragma("unroll")                                                       \
        for (int m = 0; m < 4; ++m)                                             \
          _Pragma("unroll")                                                     \
          for (int n = 0; n < 4; ++n)                                           \
            acc[m][n] = mfma16(af[ks][m], bfr[ks][n], acc[m][n]);               \
    }                                                                           \
  }

// ---------------- fused q+kv GEMM (768 blocks -> 3 blocks/CU) ----------------
__global__ __launch_bounds__(256) void gemm_qkv_k(const uint16_t* __restrict__ xn,
                                                  const uint16_t* __restrict__ mn,
                                                  const uint16_t* __restrict__ wq,
                                                  const uint16_t* __restrict__ wkv,
                                                  uint16_t* __restrict__ qb,
                                                  uint16_t* __restrict__ kb,
                                                  uint16_t* __restrict__ vt3){
  int bx = blockIdx.x;
  bool isq = bx < 256;
  const uint16_t *A, *Bt;
  int n0, m0;
  if (isq){ A = xn; Bt = wq;  n0 = (bx & 7) * 128;  m0 = (bx >> 3) * 128; }
  else    { int b2 = bx - 256; A = mn; Bt = wkv; n0 = (b2 & 3) * 128; m0 = (b2 >> 2) * 128; }
  int tid = threadIdx.x, lane = tid & 63, wid = tid >> 6;
  int wr = wid >> 1, wc = wid & 1;
  int lr = lane & 15, lq = lane >> 4;
  GEMM_BODY(A, Bt, 1024)
  #pragma unroll
  for (int m = 0; m < 4; ++m)
    #pragma unroll
    for (int n = 0; n < 4; ++n){
      int gr0 = m0 + wr*64 + m*16 + lq*4;
      int gc  = n0 + wc*64 + n*16 + lr;
      if (isq){
        #pragma unroll
        for (int r = 0; r < 4; ++r) qb[(size_t)(gr0 + r) * 1024 + gc] = f2bf(acc[m][n][r]);
      } else if (gc < 256){
        #pragma unroll
        for (int r = 0; r < 4; ++r) kb[(size_t)(gr0 + r) * 256 + gc] = f2bf(acc[m][n][r]);
      } else {
        int h = gc - 256, bb = gr0 >> 11, s0 = gr0 & 2047;
        int st = s0 >> 5, sc = (s0 >> 3) & 3, s8 = s0 & 7;   // s8 in {0,4}
        u16x4 pk;
        #pragma unroll
        for (int r = 0; r < 4; ++r) pk[r] = f2bf(acc[m][n][r]);
        *(u16x4*)&vt3[((((size_t)bb*64 + st)*4 + sc)*256 + h)*8 + s8] = pk;
      }
    }
}

// ---------------- out GEMM: C[M][N] f32 = A[M][K] * Bt[N][K]^T ----------------
__global__ __launch_bounds__(256) void gemm_out_k(const uint16_t* __restrict__ A,
                                                  const uint16_t* __restrict__ Bt,
                                                  float* __restrict__ Cf){
  int n0 = blockIdx.x * 128, m0 = blockIdx.y * 128;
  int tid = threadIdx.x, lane = tid & 63, wid = tid >> 6;
  int wr = wid >> 1, wc = wid & 1;
  int lr = lane & 15, lq = lane >> 4;
  GEMM_BODY(A, Bt, 1024)
  #pragma unroll
  for (int m = 0; m < 4; ++m)
    #pragma unroll
    for (int n = 0; n < 4; ++n){
      int gr0 = m0 + wr*64 + m*16 + lq*4;
      int gc  = n0 + wc*64 + n*16 + lr;
      #pragma unroll
      for (int r = 0; r < 4; ++r) Cf[(size_t)(gr0 + r) * 1024 + gc] = acc[m][n][r];
    }
}

// ---------------- flash attention: 64-s double-tile per barrier period ----------------
// r12 structure + barrier cadence halved: each iteration stages 64 s (K 32KB +
// V 32KB linear panels) and computes two 32-s sub-tiles. One full-drain
// __syncthreads per 64 s instead of per 32 -> drain/phase-transition overhead
// halves. LDS 128KB (1 block/CU — already reg-capped there, nothing lost).
// grid 256 = sh(2b) x qt(3b) x b(3b low, XCD pin); 512 thr = 8 waves = qs(2) x n(4).
__global__ __launch_bounds__(512, 2) void attn_k(const uint16_t* __restrict__ Q,
                                                 const uint16_t* __restrict__ Kb,
                                                 const uint16_t* __restrict__ Vt3,
                                                 const float* __restrict__ bias,
                                                 uint16_t* __restrict__ po,   // [3][4096][1024] bf16
                                                 uint16_t* __restrict__ po3,  // [4096][1024] bf16 (=d_out)
                                                 float* __restrict__ pm,
                                                 float* __restrict__ pl){
  int bx = blockIdx.x;
  int b = bx & 7, qt = (bx >> 3) & 7, sh = bx >> 6;
  int tid = threadIdx.x, lane = tid & 63, wid = tid >> 6;
  int n = wid & 3, qs = wid >> 2;
  int lc = lane & 31, hi = lane >> 5;
  __shared__ __align__(16) uint16_t Ks[2*64*256];   // [buf][s64][k], swizzled (64KB)
  __shared__ __align__(16) uint16_t Vs[2*2*4*256*8];// [buf][panel][sc][h][8s] (64KB)
  __shared__ uint32_t mask_lds[16];

  int sbeg = sh * 512;
  {
    float bv = bias[b*2048 + sbeg + tid];           // one vmem read, prologue only
    unsigned long long bal = __ballot(bv == 0.0f);  // wave wid covers s [wid*64, +64)
    if (lane == 0){
      mask_lds[wid*2]     = (uint32_t)bal;
      mask_lds[wid*2 + 1] = (uint32_t)(bal >> 32);
    }
  }

  int t0w = qt*64 + qs*32;                          // wave's 32 q-rows
  bf16x8 qf[16];
  {
    const uint16_t* qp = Q + (size_t)(b*512 + t0w + lc) * 1024 + n*256 + hi*8;
    #pragma unroll
    for (int kc = 0; kc < 16; ++kc) qf[kc] = ldbf8(qp + kc*16);
  }
  f32x16 o[8] = {};                                 // O[32q][256h]
  float mrow = -1e30f, lrow = 0.0f;

  auto STAGE = [&](int buf, int s0){                // stages 64 s-rows (K 32KB + V 32KB)
    const char* vsrc = (const char*)Vt3 + ((size_t)(b*64 + (s0 >> 5))) * 16384;
    #pragma unroll
    for (int it = 0; it < 4; ++it){
      int ob = it*8192 + tid*16;
      int krow = ob >> 9;                           // 0..63
      int kcol = (ob & 511) ^ ((krow & 7) << 4);    // pre-swizzled source
      gl16((const char*)Kb + ((size_t)(b*2048 + s0 + krow) * 256) * 2 + kcol,
           (char*)Ks + buf*32768 + it*8192 + wid*1024);
      gl16(vsrc + ob,                               // V: linear coalesced 32KB panel pair
           (char*)Vs + buf*32768 + it*8192 + wid*1024);
    }
  };

  STAGE(0, sbeg);
  __syncthreads();                                  // tile 0 + mask words ready

  #pragma unroll 1
  for (int t = 0; t < 8; ++t){
    if (t < 7) STAGE((t+1) & 1, sbeg + (t+1)*64);  // flies under this double-tile's compute
    #pragma unroll
    for (int st2 = 0; st2 < 2; ++st2){
      const uint16_t* ksb = Ks + (t & 1)*16384 + st2*8192;
      const uint16_t* vsb = Vs + (t & 1)*16384 + st2*8192;

      // swapped QK^T: C[s][q], col = q = lc, row s = (reg&3)+8*(reg>>2)+4*hi
      f32x16 sacc = {};
      __builtin_amdgcn_s_setprio(1);
      #pragma unroll
      for (int kc = 0; kc < 16; ++kc){
        bf16x8 ak = ldbf8(&ksb[lc*256 + ((kc*16 + hi*8) ^ ((lc & 7) << 3))]);
        sacc = mfma32(ak, qf[kc], sacc);
      }
      __builtin_amdgcn_s_setprio(0);

      // in-register masked online softmax (lane owns q = lc)
      uint32_t mw = mask_lds[t*2 + st2];
      int sb4 = hi * 4;
      float p[16];
      float mx = -1e30f;
      #pragma unroll
      for (int r = 0; r < 16; ++r){
        int sr = (r & 3) + 8*(r >> 2) + sb4;
        float v = ((mw >> sr) & 1u) ? sacc[r] : -1e30f;
        p[r] = v;
        mx = fmaxf(mx, v);
      }
      mx = fmaxf(mx, __shfl_xor(mx, 32));
      if (__any(mx > mrow + 8.0f)){                 // defer-max (T13)
        float mn = fmaxf(mrow, mx);
        float scl = __expf(mrow - mn);
        mrow = mn; lrow *= scl;
        #pragma unroll
        for (int ht = 0; ht < 8; ++ht) o[ht] *= scl;
      }
      float rs = 0.0f;
      #pragma unroll
      for (int r = 0; r < 16; ++r){ p[r] = __expf(p[r] - mrow); rs += p[r]; }
      rs += __shfl_xor(rs, 32);
      lrow += rs;

      // P -> bf16 A-frags in registers: cvt_pk pairs + permlane32_swap (T12)
      uint32_t w0, w1, w2, w3, w4, w5, w6, w7;
      w0 = cvtpk(p[0], p[1]);   w2 = cvtpk(p[4], p[5]);   plswap(w0, w2);
      w1 = cvtpk(p[2], p[3]);   w3 = cvtpk(p[6], p[7]);   plswap(w1, w3);
      w4 = cvtpk(p[8], p[9]);   w6 = cvtpk(p[12], p[13]); plswap(w4, w6);
      w5 = cvtpk(p[10], p[11]); w7 = cvtpk(p[14], p[15]); plswap(w5, w7);
      u32x4 t0v = {w0, w1, w2, w3};
      u32x4 t1v = {w4, w5, w6, w7};
      bf16x8 pa0 = __builtin_bit_cast(bf16x8, t0v); // k = s 0..15
      bf16x8 pa1 = __builtin_bit_cast(bf16x8, t1v); // k = s 16..31

      // PV: O[q][h], B = V[s][h] from subtiled LDS (conflict-free b128)
      __builtin_amdgcn_s_setprio(1);
      #pragma unroll
      for (int ht = 0; ht < 8; ++ht){
        bf16x8 bv0 = ldbf8(&vsb[(size_t)hi*2048       + (ht*32 + lc)*8]);
        o[ht] = mfma32(pa0, bv0, o[ht]);
        bf16x8 bv1 = ldbf8(&vsb[(size_t)(2 + hi)*2048 + (ht*32 + lc)*8]);
        o[ht] = mfma32(pa1, bv1, o[ht]);
      }
      __builtin_amdgcn_s_setprio(0);
    }
    __syncthreads();                 // full drain: next double-tile ready, buffer reusable
  }

  // epilogue: unscaled partial o (bf16) + per-q m,l
  uint16_t* pop = (sh == 3) ? po3 : po + (size_t)sh * 4194304;
  #pragma unroll
  for (int ht = 0; ht < 8; ++ht)
    #pragma unroll
    for (int r = 0; r < 16; ++r){
      int qr = (r & 3) + 8*(r >> 2) + hi*4;
      pop[(size_t)(b*512 + t0w + qr)*1024 + n*256 + ht*32 + lc] = f2bf(o[ht][r]);
    }
  if (hi == 0){
    int mlidx = sh*16384 + (b*512 + t0w + lc)*4 + n;
    pm[mlidx] = mrow;
    pl[mlidx] = lrow;
  }
}

// ---------------- merge split-S partials (4-way bf16) -> enc bf16 ----------------
__global__ __launch_bounds__(64) void merge_k(const uint16_t* __restrict__ po,
                                              const uint16_t* __restrict__ po3,
                                              const float* __restrict__ pm,
                                              const float* __restrict__ pl,
                                              uint16_t* __restrict__ enc){
  int idx = blockIdx.x;                  // 16384 = (b*512+t)*4 + n
  int row = idx >> 2, n = idx & 3;
  float m = -1e30f;
  #pragma unroll
  for (int h = 0; h < 4; ++h) m = fmaxf(m, pm[h*16384 + idx]);
  float w[4], lsum = 0.0f;
  #pragma unroll
  for (int h = 0; h < 4; ++h){
    w[h] = __expf(pm[h*16384 + idx] - m);
    lsum += pl[h*16384 + idx] * w[h];
  }
  float inv = 1.0f / lsum;
  size_t off = (size_t)row*1024 + n*256 + threadIdx.x*4;
  float acc[4] = {0.f, 0.f, 0.f, 0.f};
  #pragma unroll
  for (int h = 0; h < 4; ++h){
    const uint16_t* src = (h < 3) ? po + (size_t)h*4194304 + off : po3 + off;
    u16x4 a = *(const u16x4*)src;
    #pragma unroll
    for (int r = 0; r < 4; ++r) acc[r] += bf2f(a[r]) * w[h];
  }
  u16x4 ov;
  #pragma unroll
  for (int r = 0; r < 4; ++r) ov[r] = f2bf(acc[r] * inv);
  *(u16x4*)(enc + off) = ov;
}

// ---------------- launcher ----------------
extern "C" void kernel_launch(void* const* d_in, const int* in_sizes, int n_in,
                              void* d_out, int out_size, void* d_ws, size_t ws_size,
                              hipStream_t stream){
  const float* x    = (const float*)d_in[0];   // [8][512][1024]
  const float* mem  = (const float*)d_in[1];   // [8][2048][1024]
  const void*  mask = d_in[2];                 // [8][2048]
  const float* rms  = (const float*)d_in[3];   // [1024]
  const float* qw   = (const float*)d_in[4];   // [4][1024][256]
  const float* kvw  = (const float*)d_in[5];   // [2][1][1024][256]
  const float* ow   = (const float*)d_in[6];   // [4][256][1024]
  float* out = (float*)d_out;                  // [8][512][1024] f32
  char* ws = (char*)d_ws;

  // ws map (temporal reuse, no overlap among concurrently-live buffers):
  //  0-8MB   xn (dead after gemm_qkv) -> enc | 8-16MB qb | 16-24MB kb | 24-32MB vt3
  // 32-34MB  wq (dead after gemm_qkv) -> pm/pl (256KB each)
  // 34-35MB  wkv | 35-37MB wout | 37MB bias(64KB) | +64KB flag
  // 38-70MB  mn (dead after gemm_qkv) -> po[0..2] bf16 24MB (38-62MB)
  uint16_t* xn   = (uint16_t*)(ws + 0);
  uint16_t* enc  = (uint16_t*)(ws + 0);
  const size_t MB = 1ull << 20;
  uint16_t* qb   = (uint16_t*)(ws + 8*MB);
  uint16_t* kb   = (uint16_t*)(ws + 16*MB);
  uint16_t* vt3  = (uint16_t*)(ws + 24*MB);    // [8][64][4][256][8] bf16 panels
  uint16_t* wq   = (uint16_t*)(ws + 32*MB);
  float*    pm   = (float*)   (ws + 32*MB);                  // 256KB (reuses wq)
  float*    pl   = (float*)   (ws + 32*MB + 262144);         // 256KB
  uint16_t* wkv  = (uint16_t*)(ws + 34*MB);
  uint16_t* wout = (uint16_t*)(ws + 35*MB);
  float*    bias = (float*)   (ws + 37*MB);
  int*      flag = (int*)     (ws + 37*MB + 65536);
  uint16_t* mn   = (uint16_t*)(ws + 38*MB);
  uint16_t* po   = (uint16_t*)(ws + 38*MB);                  // [3][4096][1024] bf16
  uint16_t* po3  = (uint16_t*)out;                           // 4th partial in d_out

  hipMemsetAsync(flag, 0, 4, stream);
  detect_mask_k<<<16, 256, 0, stream>>>((const uint32_t*)mask, flag);
  expand_mask_k<<<64, 256, 0, stream>>>(mask, flag, bias);

  rmsnorm_k<<<20480, 256, 0, stream>>>(x, mem, xn, mn, rms);

  transpose_cast_all_k<<<dim3(32,32,7), dim3(32,8), 0, stream>>>(qw, kvw, ow, wq, wkv, wout);

  gemm_qkv_k<<<768, 256, 0, stream>>>(xn, mn, wq, wkv, qb, kb, vt3);

  rope_all_k<<<16384, 256, 0, stream>>>(qb, kb);

  attn_k<<<256, 512, 0, stream>>>(qb, kb, vt3, bias, po, po3, pm, pl);
  merge_k<<<16384, 64, 0, stream>>>(po, po3, pm, pl, enc);

  gemm_out_k<<<dim3(8, 32), 256, 0, stream>>>(enc, wout, out);
}

// Round 14
// 173.313 us; speedup vs baseline: 1.0460x; 1.0460x over previous
//
#include <hip/hip_runtime.h>
#include <stdint.h>

// ---------------- types & helpers ----------------
typedef __bf16   bf16x8 __attribute__((ext_vector_type(8)));
typedef float    f32x4  __attribute__((ext_vector_type(4)));
typedef float    f32x16 __attribute__((ext_vector_type(16)));
typedef uint16_t u16x8  __attribute__((ext_vector_type(8)));
typedef uint16_t u16x4  __attribute__((ext_vector_type(4)));
typedef uint32_t u32x4  __attribute__((ext_vector_type(4)));

#define DEVFN static __device__ __forceinline__

DEVFN uint16_t f2bf(float f){            // RNE f32 -> bf16
  uint32_t u = __builtin_bit_cast(uint32_t, f);
  u += 0x7fffu + ((u >> 16) & 1u);
  return (uint16_t)(u >> 16);
}
DEVFN float bf2f(uint16_t h){
  return __builtin_bit_cast(float, (uint32_t)h << 16);
}
DEVFN bf16x8 ldbf8(const uint16_t* p){
  return __builtin_bit_cast(bf16x8, *(const u16x8*)p);
}
DEVFN void gl16(const void* g, void* l){ // async global->LDS, 16B/lane, LDS base wave-uniform
  __builtin_amdgcn_global_load_lds((__attribute__((address_space(1))) void*)g,
                                   (__attribute__((address_space(3))) void*)l,
                                   16, 0, 0);
}
DEVFN f32x4 mfma16(bf16x8 a, bf16x8 b, f32x4 c){
  return __builtin_amdgcn_mfma_f32_16x16x32_bf16(a, b, c, 0, 0, 0);
}
DEVFN f32x16 mfma32(bf16x8 a, bf16x8 b, f32x16 c){
  return __builtin_amdgcn_mfma_f32_32x32x16_bf16(a, b, c, 0, 0, 0);
}
DEVFN uint32_t cvtpk(float lo, float hi){          // pack 2 f32 -> 2 bf16 in one dword
  uint32_t r;
  asm("v_cvt_pk_bf16_f32 %0, %1, %2" : "=v"(r) : "v"(lo), "v"(hi));
  return r;
}
DEVFN void plswap(uint32_t &x, uint32_t &y){       // swap x.hi-lanes <-> y.lo-lanes
  asm("v_permlane32_swap_b32 %0, %1" : "+v"(x), "+v"(y));
}

// ---------------- mask dtype detect + expand ----------------
__global__ void detect_mask_k(const uint32_t* m, int* flag){
  int i = blockIdx.x * 256 + threadIdx.x;          // 16 blocks x 256 = 4096 dwords
  uint32_t v = m[i];
  int notint   = (v > 1u) ? 1 : 0;
  int notfloat = (v != 0u && v != 0x3F800000u) ? 2 : 0;
  int bits = notint | notfloat;
  if (__any(bits)){
    int agg = bits;
    agg |= __shfl_xor(agg, 1);  agg |= __shfl_xor(agg, 2);
    agg |= __shfl_xor(agg, 4);  agg |= __shfl_xor(agg, 8);
    agg |= __shfl_xor(agg, 16); agg |= __shfl_xor(agg, 32);
    if ((threadIdx.x & 63) == 0) atomicOr(flag, agg);
  }
}

__global__ void expand_mask_k(const void* m, const int* flag, float* bias){
  int i = blockIdx.x * 256 + threadIdx.x;   // 16384 elements
  int f = *flag;
  bool on;
  if ((f & 1) == 0)      on = ((const int*)m)[i]   != 0;     // int32
  else if ((f & 2) == 0) on = ((const float*)m)[i] != 0.0f;  // float32
  else                   on = ((const uint8_t*)m)[i] != 0;   // bool bytes
  bias[i] = on ? 0.0f : -1e30f;
}

// ---------------- RMSNorm (f32 in) -> bf16 out, x and mem fused ----------------
__global__ __launch_bounds__(256) void rmsnorm_k(const float* __restrict__ x,
                                                 const float* __restrict__ mem,
                                                 uint16_t* __restrict__ xn,
                                                 uint16_t* __restrict__ mn,
                                                 const float* __restrict__ scale){
  int row = blockIdx.x;                 // 0..20479: first 4096 -> x, rest -> mem
  const float* in; uint16_t* out; int r0;
  if (row < 4096){ in = x;  out = xn; r0 = row; }
  else           { in = mem; out = mn; r0 = row - 4096; }
  const float4* ip = (const float4*)(in + (size_t)r0 * 1024);
  float4 v = ip[threadIdx.x];
  float ss = v.x*v.x + v.y*v.y + v.z*v.z + v.w*v.w;
  #pragma unroll
  for (int off = 1; off < 64; off <<= 1) ss += __shfl_xor(ss, off);
  __shared__ float wsum[4];
  if ((threadIdx.x & 63) == 0) wsum[threadIdx.x >> 6] = ss;
  __syncthreads();
  float r = rsqrtf((wsum[0] + wsum[1] + wsum[2] + wsum[3]) * (1.0f/1024.0f) + 1e-6f);
  float4 sc = ((const float4*)scale)[threadIdx.x];
  u16x4 o;
  o[0] = f2bf(v.x * r * (1.0f + sc.x));
  o[1] = f2bf(v.y * r * (1.0f + sc.y));
  o[2] = f2bf(v.z * r * (1.0f + sc.z));
  o[3] = f2bf(v.w * r * (1.0f + sc.w));
  *(u16x4*)(out + (size_t)r0 * 1024 + threadIdx.x * 4) = o;
}

// ---------------- transpose+cast: all three weights in one launch ----------------
__global__ void transpose_cast_all_k(const float* __restrict__ qw,
                                     const float* __restrict__ kvw,
                                     const float* __restrict__ ow,
                                     uint16_t* __restrict__ wq,
                                     uint16_t* __restrict__ wkv,
                                     uint16_t* __restrict__ wout){
  int z = blockIdx.z;
  const float* in; uint16_t* out; int rs, os, C;
  if (z < 4)      { in = qw  + z*262144;     out = wq  + z*262144;     rs = 256;  os = 1024; C = 256; }
  else if (z < 6) { in = kvw + (z-4)*262144; out = wkv + (z-4)*262144; rs = 256;  os = 1024; C = 256; }
  else            { in = ow;                 out = wout;               rs = 1024; os = 1024; C = 1024; }
  int c0 = blockIdx.x * 32, r0 = blockIdx.y * 32;
  if (c0 >= C) return;
  __shared__ float t[32][33];
  int tx = threadIdx.x, ty = threadIdx.y;     // (32,8)
  #pragma unroll
  for (int i = 0; i < 4; ++i)
    t[ty + 8*i][tx] = in[(size_t)(r0 + ty + 8*i) * rs + c0 + tx];
  __syncthreads();
  #pragma unroll
  for (int i = 0; i < 4; ++i)
    out[(size_t)(c0 + ty + 8*i) * os + r0 + tx] = f2bf(t[tx][ty + 8*i]);
}

// ---------------- RoPE q+k in one launch (in-place on bf16) ----------------
__global__ __launch_bounds__(256) void rope_all_k(uint16_t* q, uint16_t* kk){
  if (blockIdx.x < 8192){
    int idx = blockIdx.x * 256 + threadIdx.x;   // 2M q pairs
    int j = idx & 127, n = (idx >> 7) & 3, bt = idx >> 9;
    float inv = exp2f((float)j * (-13.287712379549449f / 128.0f)); // 10000^(-j/128)
    float rad = (float)(2048 + (bt & 511)) * inv;
    float s, c; sincosf(rad, &s, &c);
    size_t base = (size_t)bt * 1024 + n * 256 + j;
    float x1 = bf2f(q[base]), x2 = bf2f(q[base + 128]);
    q[base]       = f2bf((x1 * c - x2 * s) * 0.0625f);
    q[base + 128] = f2bf((x2 * c + x1 * s) * 0.0625f);
  } else {
    int idx = (blockIdx.x - 8192) * 256 + threadIdx.x;  // 2M k pairs
    int j = idx & 127, bs = idx >> 7;
    float inv = exp2f((float)j * (-13.287712379549449f / 128.0f));
    float rad = (float)(bs & 2047) * inv;
    float s, c; sincosf(rad, &s, &c);
    size_t base = (size_t)bs * 256 + j;
    float x1 = bf2f(kk[base]), x2 = bf2f(kk[base + 128]);
    kk[base]       = f2bf(x1 * c - x2 * s);
    kk[base + 128] = f2bf(x2 * c + x1 * s);
  }
}

// ---------------- shared GEMM body: BK=64, XOR-swizzled LDS (16-way fix) ----------------
// As/Bs rows are 128B -> linear layout would be a 16-way b128 conflict (G4);
// XOR byte ^ ((row&7)<<4) via pre-swizzled gl16 source + swizzled read.
// Measured r13: −~11us vs BK=32 across the two GEMMs.
#define GEMM_BODY(A_, Bt_, K_)                                                  \
  __shared__ __align__(16) uint16_t As[128*64];                                 \
  __shared__ __align__(16) uint16_t Bs[128*64];                                 \
  f32x4 acc[4][4] = {};                                                         \
  {                                                                             \
    const int K = (K_);                                                         \
    _Pragma("unroll 1")                                                         \
    for (int k0 = 0; k0 < K; k0 += 64){                                         \
      __syncthreads();                                                          \
      _Pragma("unroll")                                                         \
      for (int it = 0; it < 4; ++it){                                           \
        int ob = it * 4096 + tid * 16;                                          \
        int row = ob >> 7;                                                      \
        int col = (ob & 127) ^ ((row & 7) << 4);                                \
        gl16((const char*)(A_)  + ((size_t)(m0 + row) * K + k0) * 2 + col,      \
             (char*)As + it * 4096 + wid * 1024);                               \
        gl16((const char*)(Bt_) + ((size_t)(n0 + row) * K + k0) * 2 + col,      \
             (char*)Bs + it * 4096 + wid * 1024);                               \
      }                                                                         \
      __syncthreads();                                                          \
      bf16x8 af[2][4], bfr[2][4];                                               \
      _Pragma("unroll")                                                         \
      for (int ks = 0; ks < 2; ++ks){                                           \
        _Pragma("unroll")                                                       \
        for (int m = 0; m < 4; ++m)                                             \
          af[ks][m]  = ldbf8(&As[(wr*64 + m*16 + lr) * 64 +                     \
                                 ((ks*32 + lq*8) ^ ((lr & 7) << 3))]);          \
        _Pragma("unroll")                                                       \
        for (int n = 0; n < 4; ++n)                                             \
          bfr[ks][n] = ldbf8(&Bs[(wc*64 + n*16 + lr) * 64 +                     \
                                 ((ks*32 + lq*8) ^ ((lr & 7) << 3))]);          \
      }                                                                         \
      _Pragma("unroll")                                                         \
      for (int ks = 0; ks < 2; ++ks)                                            \
        _Pragma("unroll")                                                       \
        for (int m = 0; m < 4; ++m)                                             \
          _Pragma("unroll")                                                     \
          for (int n = 0; n < 4; ++n)                                           \
            acc[m][n] = mfma16(af[ks][m], bfr[ks][n], acc[m][n]);               \
    }                                                                           \
  }

// ---------------- fused q+kv GEMM (768 blocks -> 3 blocks/CU) ----------------
__global__ __launch_bounds__(256) void gemm_qkv_k(const uint16_t* __restrict__ xn,
                                                  const uint16_t* __restrict__ mn,
                                                  const uint16_t* __restrict__ wq,
                                                  const uint16_t* __restrict__ wkv,
                                                  uint16_t* __restrict__ qb,
                                                  uint16_t* __restrict__ kb,
                                                  uint16_t* __restrict__ vt3){
  int bx = blockIdx.x;
  bool isq = bx < 256;
  const uint16_t *A, *Bt;
  int n0, m0;
  if (isq){ A = xn; Bt = wq;  n0 = (bx & 7) * 128;  m0 = (bx >> 3) * 128; }
  else    { int b2 = bx - 256; A = mn; Bt = wkv; n0 = (b2 & 3) * 128; m0 = (b2 >> 2) * 128; }
  int tid = threadIdx.x, lane = tid & 63, wid = tid >> 6;
  int wr = wid >> 1, wc = wid & 1;
  int lr = lane & 15, lq = lane >> 4;
  GEMM_BODY(A, Bt, 1024)
  #pragma unroll
  for (int m = 0; m < 4; ++m)
    #pragma unroll
    for (int n = 0; n < 4; ++n){
      int gr0 = m0 + wr*64 + m*16 + lq*4;
      int gc  = n0 + wc*64 + n*16 + lr;
      if (isq){
        #pragma unroll
        for (int r = 0; r < 4; ++r) qb[(size_t)(gr0 + r) * 1024 + gc] = f2bf(acc[m][n][r]);
      } else if (gc < 256){
        #pragma unroll
        for (int r = 0; r < 4; ++r) kb[(size_t)(gr0 + r) * 256 + gc] = f2bf(acc[m][n][r]);
      } else {
        int h = gc - 256, bb = gr0 >> 11, s0 = gr0 & 2047;
        int st = s0 >> 5, sc = (s0 >> 3) & 3, s8 = s0 & 7;   // s8 in {0,4}
        u16x4 pk;
        #pragma unroll
        for (int r = 0; r < 4; ++r) pk[r] = f2bf(acc[m][n][r]);
        *(u16x4*)&vt3[((((size_t)bb*64 + st)*4 + sc)*256 + h)*8 + s8] = pk;
      }
    }
}

// ---------------- out GEMM: C[M][N] f32 = A[M][K] * Bt[N][K]^T ----------------
__global__ __launch_bounds__(256) void gemm_out_k(const uint16_t* __restrict__ A,
                                                  const uint16_t* __restrict__ Bt,
                                                  float* __restrict__ Cf){
  int n0 = blockIdx.x * 128, m0 = blockIdx.y * 128;
  int tid = threadIdx.x, lane = tid & 63, wid = tid >> 6;
  int wr = wid >> 1, wc = wid & 1;
  int lr = lane & 15, lq = lane >> 4;
  GEMM_BODY(A, Bt, 1024)
  #pragma unroll
  for (int m = 0; m < 4; ++m)
    #pragma unroll
    for (int n = 0; n < 4; ++n){
      int gr0 = m0 + wr*64 + m*16 + lq*4;
      int gc  = n0 + wc*64 + n*16 + lr;
      #pragma unroll
      for (int r = 0; r < 4; ++r) Cf[(size_t)(gr0 + r) * 1024 + gc] = acc[m][n][r];
    }
}

// ---------------- flash attention: r12 config (measured 60us) ----------------
// 32x32 MFMA, swapped QK^T, in-register softmax (T12 cvt_pk+permlane), bit-mask,
// linear V panels (vt3), triple-buffer counted-vmcnt pipeline (depth 2, vmcnt(4),
// never drained to 0 in-loop). grid 256 = sh(2b) x qt(3b) x b(3b low, XCD pin);
// 512 thr = 8 waves = qs(2) x n(4); wave owns 32 q-rows of head n; 16 tiles of 32 s.
__global__ __launch_bounds__(512, 2) void attn_k(const uint16_t* __restrict__ Q,
                                                 const uint16_t* __restrict__ Kb,
                                                 const uint16_t* __restrict__ Vt3,
                                                 const float* __restrict__ bias,
                                                 uint16_t* __restrict__ po,   // [3][4096][1024] bf16
                                                 uint16_t* __restrict__ po3,  // [4096][1024] bf16 (=d_out)
                                                 float* __restrict__ pm,
                                                 float* __restrict__ pl){
  int bx = blockIdx.x;
  int b = bx & 7, qt = (bx >> 3) & 7, sh = bx >> 6;
  int tid = threadIdx.x, lane = tid & 63, wid = tid >> 6;
  int n = wid & 3, qs = wid >> 2;
  int lc = lane & 31, hi = lane >> 5;
  __shared__ __align__(16) uint16_t Ks[3*32*256];   // [buf][s][k], swizzled
  __shared__ __align__(16) uint16_t Vs[3*4*256*8];  // [buf][sc][h][8s] = linear panel copy
  __shared__ uint32_t mask_lds[16];

  int sbeg = sh * 512;
  {
    float bv = bias[b*2048 + sbeg + tid];           // one vmem read, prologue only
    unsigned long long bal = __ballot(bv == 0.0f);  // wave wid covers s [wid*64, +64)
    if (lane == 0){
      mask_lds[wid*2]     = (uint32_t)bal;
      mask_lds[wid*2 + 1] = (uint32_t)(bal >> 32);
    }
  }

  int t0w = qt*64 + qs*32;                          // wave's 32 q-rows
  bf16x8 qf[16];
  {
    const uint16_t* qp = Q + (size_t)(b*512 + t0w + lc) * 1024 + n*256 + hi*8;
    #pragma unroll
    for (int kc = 0; kc < 16; ++kc) qf[kc] = ldbf8(qp + kc*16);
  }
  f32x16 o[8] = {};                                 // O[32q][256h]
  float mrow = -1e30f, lrow = 0.0f;

  auto STAGE = [&](int buf, int s0){
    const char* vsrc = (const char*)Vt3 + ((size_t)(b*64 + (s0 >> 5))) * 16384;
    #pragma unroll
    for (int it = 0; it < 2; ++it){
      int ob = it*8192 + tid*16;
      int krow = ob >> 9;                           // K: [32 s][512B], XOR-pre-swizzled source
      int kcol = (ob & 511) ^ ((krow & 7) << 4);
      gl16((const char*)Kb + ((size_t)(b*2048 + s0 + krow) * 256) * 2 + kcol,
           (char*)Ks + buf*16384 + it*8192 + wid*1024);
      gl16(vsrc + ob,                               // V: linear coalesced panel copy
           (char*)Vs + buf*16384 + it*8192 + wid*1024);
    }
  };

  STAGE(0, sbeg);
  STAGE(1, sbeg + 32);

  #pragma unroll 1
  for (int t = 0; t < 16; ++t){
    if (t == 0)      asm volatile("s_waitcnt vmcnt(4) lgkmcnt(0)" ::: "memory");
    else if (t < 15) asm volatile("s_waitcnt vmcnt(4)" ::: "memory");
    else             asm volatile("s_waitcnt vmcnt(0)" ::: "memory");
    __builtin_amdgcn_s_barrier();
    asm volatile("" ::: "memory");
    if (t < 14) STAGE((t+2)%3, sbeg + (t+2)*32);

    const uint16_t* ksb = Ks + (t%3)*8192;
    const uint16_t* vsb = Vs + (t%3)*8192;

    // swapped QK^T: C[s][q], col = q = lc, row s = (reg&3)+8*(reg>>2)+4*hi
    f32x16 sacc = {};
    __builtin_amdgcn_s_setprio(1);
    #pragma unroll
    for (int kc = 0; kc < 16; ++kc){
      bf16x8 ak = ldbf8(&ksb[lc*256 + ((kc*16 + hi*8) ^ ((lc & 7) << 3))]);
      sacc = mfma32(ak, qf[kc], sacc);
    }
    __builtin_amdgcn_s_setprio(0);

    // in-register masked online softmax (lane owns q = lc)
    uint32_t mw = mask_lds[t];
    int sb4 = hi * 4;
    float p[16];
    float mx = -1e30f;
    #pragma unroll
    for (int r = 0; r < 16; ++r){
      int sr = (r & 3) + 8*(r >> 2) + sb4;
      float v = ((mw >> sr) & 1u) ? sacc[r] : -1e30f;
      p[r] = v;
      mx = fmaxf(mx, v);
    }
    mx = fmaxf(mx, __shfl_xor(mx, 32));
    if (__any(mx > mrow + 8.0f)){                   // defer-max (T13)
      float mn = fmaxf(mrow, mx);
      float scl = __expf(mrow - mn);
      mrow = mn; lrow *= scl;
      #pragma unroll
      for (int ht = 0; ht < 8; ++ht) o[ht] *= scl;
    }
    float rs = 0.0f;
    #pragma unroll
    for (int r = 0; r < 16; ++r){ p[r] = __expf(p[r] - mrow); rs += p[r]; }
    rs += __shfl_xor(rs, 32);
    lrow += rs;

    // P -> bf16 A-frags in registers: cvt_pk pairs + permlane32_swap (T12)
    uint32_t w0, w1, w2, w3, w4, w5, w6, w7;
    w0 = cvtpk(p[0], p[1]);   w2 = cvtpk(p[4], p[5]);   plswap(w0, w2);
    w1 = cvtpk(p[2], p[3]);   w3 = cvtpk(p[6], p[7]);   plswap(w1, w3);
    w4 = cvtpk(p[8], p[9]);   w6 = cvtpk(p[12], p[13]); plswap(w4, w6);
    w5 = cvtpk(p[10], p[11]); w7 = cvtpk(p[14], p[15]); plswap(w5, w7);
    u32x4 t0v = {w0, w1, w2, w3};
    u32x4 t1v = {w4, w5, w6, w7};
    bf16x8 pa0 = __builtin_bit_cast(bf16x8, t0v);   // k = s 0..15
    bf16x8 pa1 = __builtin_bit_cast(bf16x8, t1v);   // k = s 16..31

    // PV: O[q][h], B = V[s][h] from subtiled LDS (conflict-free b128)
    __builtin_amdgcn_s_setprio(1);
    #pragma unroll
    for (int ht = 0; ht < 8; ++ht){
      bf16x8 bv0 = ldbf8(&vsb[(size_t)hi*2048       + (ht*32 + lc)*8]);
      o[ht] = mfma32(pa0, bv0, o[ht]);
      bf16x8 bv1 = ldbf8(&vsb[(size_t)(2 + hi)*2048 + (ht*32 + lc)*8]);
      o[ht] = mfma32(pa1, bv1, o[ht]);
    }
    __builtin_amdgcn_s_setprio(0);
  }

  // epilogue: unscaled partial o (bf16) + per-q m,l
  uint16_t* pop = (sh == 3) ? po3 : po + (size_t)sh * 4194304;
  #pragma unroll
  for (int ht = 0; ht < 8; ++ht)
    #pragma unroll
    for (int r = 0; r < 16; ++r){
      int qr = (r & 3) + 8*(r >> 2) + hi*4;
      pop[(size_t)(b*512 + t0w + qr)*1024 + n*256 + ht*32 + lc] = f2bf(o[ht][r]);
    }
  if (hi == 0){
    int mlidx = sh*16384 + (b*512 + t0w + lc)*4 + n;
    pm[mlidx] = mrow;
    pl[mlidx] = lrow;
  }
}

// ---------------- merge split-S partials (4-way bf16) -> enc bf16 ----------------
__global__ __launch_bounds__(64) void merge_k(const uint16_t* __restrict__ po,
                                              const uint16_t* __restrict__ po3,
                                              const float* __restrict__ pm,
                                              const float* __restrict__ pl,
                                              uint16_t* __restrict__ enc){
  int idx = blockIdx.x;                  // 16384 = (b*512+t)*4 + n
  int row = idx >> 2, n = idx & 3;
  float m = -1e30f;
  #pragma unroll
  for (int h = 0; h < 4; ++h) m = fmaxf(m, pm[h*16384 + idx]);
  float w[4], lsum = 0.0f;
  #pragma unroll
  for (int h = 0; h < 4; ++h){
    w[h] = __expf(pm[h*16384 + idx] - m);
    lsum += pl[h*16384 + idx] * w[h];
  }
  float inv = 1.0f / lsum;
  size_t off = (size_t)row*1024 + n*256 + threadIdx.x*4;
  float acc[4] = {0.f, 0.f, 0.f, 0.f};
  #pragma unroll
  for (int h = 0; h < 4; ++h){
    const uint16_t* src = (h < 3) ? po + (size_t)h*4194304 + off : po3 + off;
    u16x4 a = *(const u16x4*)src;
    #pragma unroll
    for (int r = 0; r < 4; ++r) acc[r] += bf2f(a[r]) * w[h];
  }
  u16x4 ov;
  #pragma unroll
  for (int r = 0; r < 4; ++r) ov[r] = f2bf(acc[r] * inv);
  *(u16x4*)(enc + off) = ov;
}

// ---------------- launcher ----------------
extern "C" void kernel_launch(void* const* d_in, const int* in_sizes, int n_in,
                              void* d_out, int out_size, void* d_ws, size_t ws_size,
                              hipStream_t stream){
  const float* x    = (const float*)d_in[0];   // [8][512][1024]
  const float* mem  = (const float*)d_in[1];   // [8][2048][1024]
  const void*  mask = d_in[2];                 // [8][2048]
  const float* rms  = (const float*)d_in[3];   // [1024]
  const float* qw   = (const float*)d_in[4];   // [4][1024][256]
  const float* kvw  = (const float*)d_in[5];   // [2][1][1024][256]
  const float* ow   = (const float*)d_in[6];   // [4][256][1024]
  float* out = (float*)d_out;                  // [8][512][1024] f32
  char* ws = (char*)d_ws;

  // ws map (temporal reuse, no overlap among concurrently-live buffers):
  //  0-8MB   xn (dead after gemm_qkv) -> enc | 8-16MB qb | 16-24MB kb | 24-32MB vt3
  // 32-34MB  wq (dead after gemm_qkv) -> pm/pl (256KB each)
  // 34-35MB  wkv | 35-37MB wout | 37MB bias(64KB) | +64KB flag
  // 38-70MB  mn (dead after gemm_qkv) -> po[0..2] bf16 24MB (38-62MB)
  uint16_t* xn   = (uint16_t*)(ws + 0);
  uint16_t* enc  = (uint16_t*)(ws + 0);
  const size_t MB = 1ull << 20;
  uint16_t* qb   = (uint16_t*)(ws + 8*MB);
  uint16_t* kb   = (uint16_t*)(ws + 16*MB);
  uint16_t* vt3  = (uint16_t*)(ws + 24*MB);    // [8][64][4][256][8] bf16 panels
  uint16_t* wq   = (uint16_t*)(ws + 32*MB);
  float*    pm   = (float*)   (ws + 32*MB);                  // 256KB (reuses wq)
  float*    pl   = (float*)   (ws + 32*MB + 262144);         // 256KB
  uint16_t* wkv  = (uint16_t*)(ws + 34*MB);
  uint16_t* wout = (uint16_t*)(ws + 35*MB);
  float*    bias = (float*)   (ws + 37*MB);
  int*      flag = (int*)     (ws + 37*MB + 65536);
  uint16_t* mn   = (uint16_t*)(ws + 38*MB);
  uint16_t* po   = (uint16_t*)(ws + 38*MB);                  // [3][4096][1024] bf16
  uint16_t* po3  = (uint16_t*)out;                           // 4th partial in d_out

  hipMemsetAsync(flag, 0, 4, stream);
  detect_mask_k<<<16, 256, 0, stream>>>((const uint32_t*)mask, flag);
  expand_mask_k<<<64, 256, 0, stream>>>(mask, flag, bias);

  rmsnorm_k<<<20480, 256, 0, stream>>>(x, mem, xn, mn, rms);

  transpose_cast_all_k<<<dim3(32,32,7), dim3(32,8), 0, stream>>>(qw, kvw, ow, wq, wkv, wout);

  gemm_qkv_k<<<768, 256, 0, stream>>>(xn, mn, wq, wkv, qb, kb, vt3);

  rope_all_k<<<16384, 256, 0, stream>>>(qb, kb);

  attn_k<<<256, 512, 0, stream>>>(qb, kb, vt3, bias, po, po3, pm, pl);
  merge_k<<<16384, 64, 0, stream>>>(po, po3, pm, pl, enc);

  gemm_out_k<<<dim3(8, 32), 256, 0, stream>>>(enc, wout, out);
}